// Round 4
// baseline (204.199 us; speedup 1.0000x reference)
//
#include <hip/hip_runtime.h>
#include <hip/hip_bf16.h>
#include <stdint.h>

#define NROWS 6144
#define MCOLS 6144
#define DDIM  128
#define EPSQ  1e-12f
#define NTC   48          // tiles per side (6144/128)

typedef unsigned long long ull;
typedef __attribute__((ext_vector_type(8))) short short8;
typedef __attribute__((ext_vector_type(4))) float floatx4;

// Order-preserving key: max key == max float value, ties -> smallest index.
__device__ __forceinline__ ull makeKey(float v, int idx) {
    unsigned u = __float_as_uint(v);
    u = (u & 0x80000000u) ? ~u : (u | 0x80000000u);
    return ((ull)u << 32) | (ull)(0xFFFFFFFFu - (unsigned)idx);
}
__device__ __forceinline__ int decodeKeyIdx(ull k) {
    return (int)(0xFFFFFFFFu - (unsigned)(k & 0xFFFFFFFFull));
}
__device__ __forceinline__ unsigned short f2bf(float f) {   // RNE
    unsigned u = __float_as_uint(f);
    u += 0x7fffu + ((u >> 16) & 1);
    return (unsigned short)(u >> 16);
}

#define GLOAD16(g, l) \
  __builtin_amdgcn_global_load_lds((const __attribute__((address_space(1))) unsigned int*)(g), \
                                   (__attribute__((address_space(3))) unsigned int*)(l), 16, 0, 0)

// XCD-chunked tile swizzle: hardware assigns block b -> XCD b%8; give each XCD
// a contiguous run of tile-rows so its L2 keeps the whole s2 panel resident.
__device__ __forceinline__ void tileCoord(int& rowBase, int& colBase) {
    int id  = blockIdx.x;
    int wid = (id & 7) * (NTC * NTC / 8) + (id >> 3);
    rowBase = (wid / NTC) * 128;
    colBase = (wid % NTC) * 128;
}

// ---------------- K0: convert to pre-swizzled bf16 hi|lo panels + sqnorms ----
// [row][256] bf16; elems 0-127 = hi(k), 128-255 = lo(k); pos p = k ^ ((row&7)<<3).
__global__ __launch_bounds__(256) void convert_kernel(
    const float* __restrict__ d1, const float* __restrict__ d2,
    unsigned short* __restrict__ s1, unsigned short* __restrict__ s2,
    float* __restrict__ sq1, float* __restrict__ sq2)
{
    int gw = (blockIdx.x * 256 + threadIdx.x) >> 6;   // one wave per row
    int lane = threadIdx.x & 63;
    if (gw >= NROWS + MCOLS) return;
    bool isA = gw < NROWS;
    int row = isA ? gw : gw - NROWS;
    const float* src = (isA ? d1 : d2) + (size_t)row * DDIM;
    unsigned short* dst = (isA ? s1 : s2) + (size_t)row * 256;

    float2 v = *(const float2*)(src + lane * 2);
    float s = v.x * v.x + v.y * v.y;
    #pragma unroll
    for (int m = 1; m < 64; m <<= 1) s += __shfl_xor(s, m, 64);
    if (lane == 0) { if (isA) sq1[row] = s; else sq2[row] = s; }

    unsigned short h0 = f2bf(v.x), h1 = f2bf(v.y);
    float r0 = v.x - __uint_as_float((unsigned)h0 << 16);
    float r1 = v.y - __uint_as_float((unsigned)h1 << 16);
    unsigned short l0 = f2bf(r0), l1 = f2bf(r1);
    int p = (2 * lane) ^ ((row & 7) << 3);            // pair stays adjacent
    *(unsigned*)(dst + p)       = (unsigned)h0 | ((unsigned)h1 << 16);
    *(unsigned*)(dst + p + 128) = (unsigned)l0 | ((unsigned)l1 << 16);
}

// Shared MFMA core: stage panels into LDS, run split-K bf16 MFMA.
// 128x128 tile, 512 threads = 8 waves (wr 0..1 x wc 0..3), wave tile 64x32.
// SWAPPED operands: mfma(B,A) => lane holds row=l15, cols=(lane>>4)*4+reg.
__device__ __forceinline__ void mfma_core(
    const unsigned short* __restrict__ s1, const unsigned short* __restrict__ s2,
    unsigned short* As, unsigned short* Bs,
    int rowBase, int colBase, int lane, int wave, int wr, int wc,
    floatx4 acc[4][2])
{
    {
        const unsigned short* gA = s1 + (size_t)rowBase * 256;
        const unsigned short* gB = s2 + (size_t)colBase * 256;
        int wb = wave * 512;
        #pragma unroll
        for (int it = 0; it < 8; ++it) {
            int e = wb + it * 4096;
            GLOAD16(gA + e + lane * 8, &As[e]);
            GLOAD16(gB + e + lane * 8, &Bs[e]);
        }
    }
    __syncthreads();

    const int l15 = lane & 15;
    const int kpl = (lane >> 4) * 16;     // byte offset of lane's k-chunk
    const int sw  = (lane & 7) << 4;      // xor swizzle
    int aRowB[4], bRowB[2];
    #pragma unroll
    for (int mi = 0; mi < 4; ++mi) aRowB[mi] = (wr * 64 + mi * 16 + l15) * 512;
    #pragma unroll
    for (int ni = 0; ni < 2; ++ni) bRowB[ni] = (wc * 32 + ni * 16 + l15) * 512;

    const char* Ab = (const char*)As;
    const char* Bb = (const char*)Bs;
    #pragma unroll
    for (int p = 0; p < 3; ++p) {
        const int Aoff = (p == 1) ? 256 : 0;   // lo half of A (bytes)
        const int Boff = (p == 2) ? 256 : 0;   // lo half of B
        #pragma unroll
        for (int ks = 0; ks < 4; ++ks) {
            const int kk = (ks * 64 + kpl) ^ sw;
            short8 af[4], bf[2];
            #pragma unroll
            for (int mi = 0; mi < 4; ++mi)
                af[mi] = *(const short8*)(Ab + aRowB[mi] + Aoff + kk);
            #pragma unroll
            for (int ni = 0; ni < 2; ++ni)
                bf[ni] = *(const short8*)(Bb + bRowB[ni] + Boff + kk);
            #pragma unroll
            for (int mi = 0; mi < 4; ++mi)
                #pragma unroll
                for (int ni = 0; ni < 2; ++ni)
                    acc[mi][ni] = __builtin_amdgcn_mfma_f32_16x16x32_bf16(
                        bf[ni], af[mi], acc[mi][ni], 0, 0, 0);   // SWAPPED
        }
    }
}

// ---------------- K1: GEMM -> affinity -> row/col reductions ONLY ----------
__global__ __launch_bounds__(512) void gemm_reduce_kernel(
    const unsigned short* __restrict__ s1, const unsigned short* __restrict__ s2,
    const float* __restrict__ invT,
    const float* __restrict__ sq1, const float* __restrict__ sq2,
    float* __restrict__ rowsum, float* __restrict__ colsum,
    ull* __restrict__ rowkey, ull* __restrict__ colkey)
{
    __shared__ unsigned short As[128 * 256];   // 64 KB
    __shared__ unsigned short Bs[128 * 256];   // 64 KB
    __shared__ float lRowS[128], lColS[128];
    __shared__ ull   lRowK[128], lColK[128];

    const int t = threadIdx.x;
    const int lane = t & 63;
    const int wave = t >> 6;
    const int wr = wave >> 2, wc = wave & 3;
    int rowBase, colBase;
    tileCoord(rowBase, colBase);

    if (t < 128) { lRowS[t] = 0.f; lColS[t] = 0.f; lRowK[t] = 0ull; lColK[t] = 0ull; }

    floatx4 acc[4][2] = {};
    mfma_core(s1, s2, As, Bs, rowBase, colBase, lane, wave, wr, wc, acc);

    const int l15 = lane & 15;
    const int q   = lane >> 4;
    const float iT = *invT;
    float s1r[4];
    #pragma unroll
    for (int mi = 0; mi < 4; ++mi) s1r[mi] = sq1[rowBase + wr * 64 + mi * 16 + l15];
    const int colLoc0 = wc * 32 + q * 4;
    float4 s2v[2];
    #pragma unroll
    for (int ni = 0; ni < 2; ++ni)
        s2v[ni] = *(const float4*)(sq2 + colBase + colLoc0 + ni * 16);

    float rs[4], rv[4]; int rj[4];
    float cs[2][4], cv[2][4]; int ci[2][4];
    #pragma unroll
    for (int ni = 0; ni < 2; ++ni)
        #pragma unroll
        for (int r = 0; r < 4; ++r) { cs[ni][r] = 0.f; cv[ni][r] = -1e30f; ci[ni][r] = 0; }

    #pragma unroll
    for (int mi = 0; mi < 4; ++mi) {
        const int gi = rowBase + wr * 64 + mi * 16 + l15;
        rs[mi] = 0.f; rv[mi] = -1e30f; rj[mi] = 0;
        #pragma unroll
        for (int ni = 0; ni < 2; ++ni) {
            #pragma unroll
            for (int r = 0; r < 4; ++r) {
                float sv2 = (r == 0) ? s2v[ni].x : (r == 1) ? s2v[ni].y
                          : (r == 2) ? s2v[ni].z : s2v[ni].w;
                float dd = s1r[mi] + sv2 - 2.0f * acc[mi][ni][r];
                float v = -iT * __builtin_amdgcn_sqrtf(fmaxf(dd, 0.0f) + EPSQ);
                float e = __expf(v);
                rs[mi] += e;
                if (v > rv[mi]) { rv[mi] = v; rj[mi] = colBase + colLoc0 + ni * 16 + r; }
                cs[ni][r] += e;
                if (v > cv[ni][r]) { cv[ni][r] = v; ci[ni][r] = gi; }
            }
        }
    }

    // row reduce across col-quarters (lanes differing in bits 4,5)
    #pragma unroll
    for (int mi = 0; mi < 4; ++mi) {
        float s = rs[mi], v = rv[mi]; int j = rj[mi];
        #pragma unroll
        for (int m = 16; m < 64; m <<= 1) {
            s += __shfl_xor(s, m, 64);
            float ov = __shfl_xor(v, m, 64);
            int oj = __shfl_xor(j, m, 64);
            if (ov > v || (ov == v && oj < j)) { v = ov; j = oj; }
        }
        if (lane < 16) {
            int idx = wr * 64 + mi * 16 + l15;
            atomicAdd(&lRowS[idx], s);
            atomicMax(&lRowK[idx], makeKey(v, j));
        }
    }

    // col reduce across l15 lanes (rows)
    #pragma unroll
    for (int ni = 0; ni < 2; ++ni)
        #pragma unroll
        for (int r = 0; r < 4; ++r) {
            float s = cs[ni][r], v = cv[ni][r]; int i = ci[ni][r];
            #pragma unroll
            for (int m = 1; m < 16; m <<= 1) {
                s += __shfl_xor(s, m, 64);
                float ov = __shfl_xor(v, m, 64);
                int oi = __shfl_xor(i, m, 64);
                if (ov > v || (ov == v && oi < i)) { v = ov; i = oi; }
            }
            if (l15 == 0) {
                int idx = colLoc0 + ni * 16 + r;
                atomicAdd(&lColS[idx], s);
                atomicMax(&lColK[idx], makeKey(v, i));
            }
        }
    __syncthreads();

    if (t < 128) {
        atomicAdd(&rowsum[rowBase + t], lRowS[t]);
        atomicMax(&rowkey[rowBase + t], lRowK[t]);
    } else if (t < 256) {
        int j = t - 128;
        atomicAdd(&colsum[colBase + j], lColS[j]);
        atomicMax(&colkey[colBase + j], lColK[j]);
    }
}

// ---------------- K2: per-row/col LSE + matches + cycle (merged) ------------
__global__ __launch_bounds__(256) void finalize_small_kernel(
    const float* __restrict__ rowsum, const ull* __restrict__ rowkey,
    const float* __restrict__ colsum, const ull* __restrict__ colkey,
    float* __restrict__ rowlse, float* __restrict__ collse,
    float* __restrict__ out_matches, float* __restrict__ out_cyc)
{
    int i = blockIdx.x * 256 + threadIdx.x;      // N == M
    if (i >= NROWS) return;
    rowlse[i] = logf(rowsum[i]);
    collse[i] = logf(colsum[i]);
    int mi = decodeKeyIdx(rowkey[i]);
    out_matches[i]         = (float)i;
    out_matches[NROWS + i] = (float)mi;
    out_cyc[i] = (decodeKeyIdx(colkey[mi]) == i) ? 1.0f : 0.0f;
}

// ---------------- K3: GEMM again -> write dense_logp + dense_p --------------
__global__ __launch_bounds__(512) void gemm_write_kernel(
    const unsigned short* __restrict__ s1, const unsigned short* __restrict__ s2,
    const float* __restrict__ invT,
    const float* __restrict__ sq1, const float* __restrict__ sq2,
    const float* __restrict__ rowlse, const float* __restrict__ collse,
    float* __restrict__ logp_out, float* __restrict__ p_out)
{
    __shared__ unsigned short As[128 * 256];   // 64 KB
    __shared__ unsigned short Bs[128 * 256];   // 64 KB

    const int t = threadIdx.x;
    const int lane = t & 63;
    const int wave = t >> 6;
    const int wr = wave >> 2, wc = wave & 3;
    int rowBase, colBase;
    tileCoord(rowBase, colBase);

    floatx4 acc[4][2] = {};
    mfma_core(s1, s2, As, Bs, rowBase, colBase, lane, wave, wr, wc, acc);

    const int l15 = lane & 15;
    const int q   = lane >> 4;
    const float iT = *invT;
    float s1r[4], rl[4];
    #pragma unroll
    for (int mi = 0; mi < 4; ++mi) {
        int gi = rowBase + wr * 64 + mi * 16 + l15;
        s1r[mi] = sq1[gi];
        rl[mi]  = rowlse[gi];
    }
    const int colLoc0 = wc * 32 + q * 4;
    float4 s2v[2], clv[2];
    #pragma unroll
    for (int ni = 0; ni < 2; ++ni) {
        s2v[ni] = *(const float4*)(sq2    + colBase + colLoc0 + ni * 16);
        clv[ni] = *(const float4*)(collse + colBase + colLoc0 + ni * 16);
    }

    #pragma unroll
    for (int mi = 0; mi < 4; ++mi) {
        const int gi = rowBase + wr * 64 + mi * 16 + l15;
        #pragma unroll
        for (int ni = 0; ni < 2; ++ni) {
            float4 ov, pv;
            #pragma unroll
            for (int r = 0; r < 4; ++r) {
                float sv2 = (r == 0) ? s2v[ni].x : (r == 1) ? s2v[ni].y
                          : (r == 2) ? s2v[ni].z : s2v[ni].w;
                float cl  = (r == 0) ? clv[ni].x : (r == 1) ? clv[ni].y
                          : (r == 2) ? clv[ni].z : clv[ni].w;
                float dd = s1r[mi] + sv2 - 2.0f * acc[mi][ni][r];
                float v = -iT * __builtin_amdgcn_sqrtf(fmaxf(dd, 0.0f) + EPSQ);
                float o = (v - rl[mi]) + (v - cl);
                ((float*)&ov)[r] = o;
                ((float*)&pv)[r] = __expf(o);
            }
            size_t off = (size_t)gi * MCOLS + colBase + colLoc0 + ni * 16;
            *(float4*)(logp_out + off) = ov;
            *(float4*)(p_out + off)    = pv;
        }
    }
}

extern "C" void kernel_launch(void* const* d_in, const int* in_sizes, int n_in,
                              void* d_out, int out_size, void* d_ws, size_t ws_size,
                              hipStream_t stream) {
    const float* d1   = (const float*)d_in[0];
    const float* d2   = (const float*)d_in[1];
    const float* invT = (const float*)d_in[2];

    float* out     = (float*)d_out;
    float* logp    = out;
    float* pout    = out + (size_t)NROWS * MCOLS;
    float* matches = out + 2ull * NROWS * MCOLS;
    float* cyc     = matches + 2 * NROWS;

    char* ws = (char*)d_ws;
    float* rowsum = (float*)(ws + 0);
    float* colsum = (float*)(ws + 24576);
    ull*   rowkey = (ull*)(ws + 49152);
    ull*   colkey = (ull*)(ws + 98304);
    float* sq1    = (float*)(ws + 147456);
    float* sq2    = (float*)(ws + 172032);
    float* rowlse = (float*)(ws + 196608);
    float* collse = (float*)(ws + 221184);
    unsigned short* s1 = (unsigned short*)(ws + 270336);            // [N][256] bf16
    unsigned short* s2 = (unsigned short*)(ws + 270336 + 3145728);  // [M][256] bf16

    hipMemsetAsync(d_ws, 0, 147456, stream);           // rowsum/colsum/rowkey/colkey

    convert_kernel<<<(NROWS + MCOLS) / 4, 256, 0, stream>>>(d1, d2, s1, s2, sq1, sq2);

    gemm_reduce_kernel<<<NTC * NTC, 512, 0, stream>>>(
        s1, s2, invT, sq1, sq2, rowsum, colsum, rowkey, colkey);

    finalize_small_kernel<<<NROWS / 256, 256, 0, stream>>>(
        rowsum, rowkey, colsum, colkey, rowlse, collse, matches, cyc);

    gemm_write_kernel<<<NTC * NTC, 512, 0, stream>>>(
        s1, s2, invT, sq1, sq2, rowlse, collse, logp, pout);
}

// Round 6
// 185.477 us; speedup vs baseline: 1.1009x; 1.1009x over previous
//
#include <hip/hip_runtime.h>
#include <hip/hip_bf16.h>
#include <stdint.h>

#define NROWS 6144
#define MCOLS 6144
#define DDIM  128
#define EPSQ  1e-12f
#define NTC   48          // tiles per side (6144/128)

typedef unsigned long long ull;
typedef __attribute__((ext_vector_type(8))) short short8;
typedef __attribute__((ext_vector_type(4))) float floatx4;

// Order-preserving key: max key == max float value, ties -> smallest index.
__device__ __forceinline__ ull makeKey(float v, int idx) {
    unsigned u = __float_as_uint(v);
    u = (u & 0x80000000u) ? ~u : (u | 0x80000000u);
    return ((ull)u << 32) | (ull)(0xFFFFFFFFu - (unsigned)idx);
}
__device__ __forceinline__ int decodeKeyIdx(ull k) {
    return (int)(0xFFFFFFFFu - (unsigned)(k & 0xFFFFFFFFull));
}
__device__ __forceinline__ unsigned short f2bf(float f) {   // RNE
    unsigned u = __float_as_uint(f);
    u += 0x7fffu + ((u >> 16) & 1);
    return (unsigned short)(u >> 16);
}

#define GLOAD16(g, l) \
  __builtin_amdgcn_global_load_lds((const __attribute__((address_space(1))) unsigned int*)(g), \
                                   (__attribute__((address_space(3))) unsigned int*)(l), 16, 0, 0)

// XCD-chunked tile swizzle: block b -> XCD b%8; give each XCD a contiguous
// run of tile-rows so its L2 keeps the whole s2 panel resident.
__device__ __forceinline__ void tileCoord(int& rowBase, int& colBase) {
    int id  = blockIdx.x;
    int wid = (id & 7) * (NTC * NTC / 8) + (id >> 3);
    rowBase = (wid / NTC) * 128;
    colBase = (wid % NTC) * 128;
}

// ---------------- K0: convert to chunk-major pre-swizzled bf16 panels -------
// Per row 256 bf16: [chunk0: hi(k=0..63)|lo(k=0..63)][chunk1: hi(64..127)|lo].
// Within each 64-elem half, position e' = e ^ ((row&7)<<3).
__global__ __launch_bounds__(256) void convert_kernel(
    const float* __restrict__ d1, const float* __restrict__ d2,
    unsigned short* __restrict__ s1, unsigned short* __restrict__ s2,
    float* __restrict__ sq1, float* __restrict__ sq2)
{
    int gw = (blockIdx.x * 256 + threadIdx.x) >> 6;   // one wave per row
    int lane = threadIdx.x & 63;
    if (gw >= NROWS + MCOLS) return;
    bool isA = gw < NROWS;
    int row = isA ? gw : gw - NROWS;
    const float* src = (isA ? d1 : d2) + (size_t)row * DDIM;
    unsigned short* dst = (isA ? s1 : s2) + (size_t)row * 256;

    float2 v = *(const float2*)(src + lane * 2);
    float s = v.x * v.x + v.y * v.y;
    #pragma unroll
    for (int m = 1; m < 64; m <<= 1) s += __shfl_xor(s, m, 64);
    if (lane == 0) { if (isA) sq1[row] = s; else sq2[row] = s; }

    unsigned short h0 = f2bf(v.x), h1 = f2bf(v.y);
    float r0 = v.x - __uint_as_float((unsigned)h0 << 16);
    float r1 = v.y - __uint_as_float((unsigned)h1 << 16);
    unsigned short l0 = f2bf(r0), l1 = f2bf(r1);
    int c  = lane >> 5;                         // k-chunk (k = 2*lane)
    int e  = (2 * lane) & 63;                   // even; swizzle keeps pair adjacent
    int pe = e ^ ((row & 7) << 3);
    *(unsigned*)(dst + c * 128 + pe)      = (unsigned)h0 | ((unsigned)h1 << 16);
    *(unsigned*)(dst + c * 128 + 64 + pe) = (unsigned)l0 | ((unsigned)l1 << 16);
}

// Compute one 64-K chunk: 3 split passes (hh, lo*hi, hi*lo) x 2 k-steps.
// LDS layout: [128 rows][128] = [hi 64 | lo 64], swizzled within halves.
// SWAPPED operands: mfma(B,A) => lane holds row=l15, cols=(lane>>4)*4+reg.
__device__ __forceinline__ void mfma_chunk_compute(
    const unsigned short* As, const unsigned short* Bs,
    int lane, int wr, int wc, floatx4 acc[4][2])
{
    const int l15 = lane & 15;
    const int q16 = (lane >> 4) * 16;     // byte offset of lane's k-sub
    const int sw  = (l15 & 7) << 4;       // xor swizzle (bytes)
    const char* Ab = (const char*)As;
    const char* Bb = (const char*)Bs;
    int aRowB[4], bRowB[2];
    #pragma unroll
    for (int mi = 0; mi < 4; ++mi) aRowB[mi] = (wr * 64 + mi * 16 + l15) * 256;
    #pragma unroll
    for (int ni = 0; ni < 2; ++ni) bRowB[ni] = (wc * 32 + ni * 16 + l15) * 256;

    #pragma unroll
    for (int p = 0; p < 3; ++p) {
        const int Ah = (p == 1) ? 128 : 0;   // lo half of A (bytes)
        const int Bh = (p == 2) ? 128 : 0;   // lo half of B
        #pragma unroll
        for (int ks = 0; ks < 2; ++ks) {
            const int kk = (ks * 64 + q16) ^ sw;
            short8 af[4], bf[2];
            #pragma unroll
            for (int mi = 0; mi < 4; ++mi)
                af[mi] = *(const short8*)(Ab + aRowB[mi] + Ah + kk);
            #pragma unroll
            for (int ni = 0; ni < 2; ++ni)
                bf[ni] = *(const short8*)(Bb + bRowB[ni] + Bh + kk);
            #pragma unroll
            for (int mi = 0; mi < 4; ++mi)
                #pragma unroll
                for (int ni = 0; ni < 2; ++ni)
                    acc[mi][ni] = __builtin_amdgcn_mfma_f32_16x16x32_bf16(
                        bf[ni], af[mi], acc[mi][ni], 0, 0, 0);   // SWAPPED
        }
    }
}

// Stage-and-compute both chunks. LDS: As/Bs 16K elems (32 KB) each.
__device__ __forceinline__ void mfma_core(
    const unsigned short* __restrict__ s1g, const unsigned short* __restrict__ s2g,
    unsigned short* As, unsigned short* Bs,
    int rowBase, int colBase, int lane, int wave, int wr, int wc,
    floatx4 acc[4][2])
{
    const unsigned short* gA = s1g + (size_t)rowBase * 256;
    const unsigned short* gB = s2g + (size_t)colBase * 256;
    #pragma unroll
    for (int c = 0; c < 2; ++c) {
        if (c) __syncthreads();            // all reads of chunk 0 done
        #pragma unroll
        for (int it = 0; it < 4; ++it) {
            int li = wave * 512 + it * 4096 + lane * 8;    // LDS elem idx
            int gi = li + ((li >> 7) + c) * 128;           // global elem idx
            GLOAD16(gA + gi, &As[li]);
            GLOAD16(gB + gi, &Bs[li]);
        }
        __syncthreads();                   // drains vmcnt before reads
        mfma_chunk_compute(As, Bs, lane, wr, wc, acc);
    }
}

// ---------------- K1: GEMM -> affinity -> row/col reductions ONLY ----------
__global__ __launch_bounds__(512, 4) void gemm_reduce_kernel(
    const unsigned short* __restrict__ s1, const unsigned short* __restrict__ s2,
    const float* __restrict__ invT,
    const float* __restrict__ sq1, const float* __restrict__ sq2,
    float* __restrict__ rowsum, float* __restrict__ colsum,
    ull* __restrict__ rowkey, ull* __restrict__ colkey)
{
    __shared__ unsigned short As[128 * 128];   // 32 KB
    __shared__ unsigned short Bs[128 * 128];   // 32 KB
    __shared__ float lRowS[128], lColS[128];
    __shared__ ull   lRowK[128], lColK[128];

    const int t = threadIdx.x;
    const int lane = t & 63;
    const int wave = t >> 6;
    const int wr = wave >> 2, wc = wave & 3;
    int rowBase, colBase;
    tileCoord(rowBase, colBase);

    if (t < 128) { lRowS[t] = 0.f; lColS[t] = 0.f; lRowK[t] = 0ull; lColK[t] = 0ull; }

    floatx4 acc[4][2] = {};
    mfma_core(s1, s2, As, Bs, rowBase, colBase, lane, wave, wr, wc, acc);

    const int l15 = lane & 15;
    const int q   = lane >> 4;
    const float iT = *invT;
    float s1r[4];
    #pragma unroll
    for (int mi = 0; mi < 4; ++mi)
        s1r[mi] = sq1[rowBase + wr * 64 + mi * 16 + l15] + EPSQ;
    const int colLoc0 = wc * 32 + q * 4;
    float4 s2v[2];
    #pragma unroll
    for (int ni = 0; ni < 2; ++ni)
        s2v[ni] = *(const float4*)(sq2 + colBase + colLoc0 + ni * 16);

    float rs[4], rv[4]; int rj[4];
    float cs[2][4], cv[2][4]; int ci[2][4];
    #pragma unroll
    for (int ni = 0; ni < 2; ++ni)
        #pragma unroll
        for (int r = 0; r < 4; ++r) { cs[ni][r] = 0.f; cv[ni][r] = -1e30f; ci[ni][r] = 0; }

    #pragma unroll
    for (int mi = 0; mi < 4; ++mi) {
        const int gi = rowBase + wr * 64 + mi * 16 + l15;
        rs[mi] = 0.f; rv[mi] = -1e30f; rj[mi] = 0;
        #pragma unroll
        for (int ni = 0; ni < 2; ++ni) {
            #pragma unroll
            for (int r = 0; r < 4; ++r) {
                float sv2 = (r == 0) ? s2v[ni].x : (r == 1) ? s2v[ni].y
                          : (r == 2) ? s2v[ni].z : s2v[ni].w;
                float dd = s1r[mi] + sv2 - 2.0f * acc[mi][ni][r];
                float v = -iT * __builtin_amdgcn_sqrtf(fmaxf(dd, EPSQ));
                float e = __expf(v);
                rs[mi] += e;
                if (v > rv[mi]) { rv[mi] = v; rj[mi] = colBase + colLoc0 + ni * 16 + r; }
                cs[ni][r] += e;
                if (v > cv[ni][r]) { cv[ni][r] = v; ci[ni][r] = gi; }
            }
        }
    }

    // row reduce across col-quarters (lanes differing in bits 4,5)
    #pragma unroll
    for (int mi = 0; mi < 4; ++mi) {
        float s = rs[mi], v = rv[mi]; int j = rj[mi];
        #pragma unroll
        for (int m = 16; m < 64; m <<= 1) {
            s += __shfl_xor(s, m, 64);
            float ov = __shfl_xor(v, m, 64);
            int oj = __shfl_xor(j, m, 64);
            if (ov > v || (ov == v && oj < j)) { v = ov; j = oj; }
        }
        if (lane < 16) {
            int idx = wr * 64 + mi * 16 + l15;
            atomicAdd(&lRowS[idx], s);
            atomicMax(&lRowK[idx], makeKey(v, j));
        }
    }

    // col reduce across l15 lanes (rows)
    #pragma unroll
    for (int ni = 0; ni < 2; ++ni)
        #pragma unroll
        for (int r = 0; r < 4; ++r) {
            float s = cs[ni][r], v = cv[ni][r]; int i = ci[ni][r];
            #pragma unroll
            for (int m = 1; m < 16; m <<= 1) {
                s += __shfl_xor(s, m, 64);
                float ov = __shfl_xor(v, m, 64);
                int oi = __shfl_xor(i, m, 64);
                if (ov > v || (ov == v && oi < i)) { v = ov; i = oi; }
            }
            if (l15 == 0) {
                int idx = colLoc0 + ni * 16 + r;
                atomicAdd(&lColS[idx], s);
                atomicMax(&lColK[idx], makeKey(v, i));
            }
        }
    __syncthreads();

    if (t < 128) {
        atomicAdd(&rowsum[rowBase + t], lRowS[t]);
        atomicMax(&rowkey[rowBase + t], lRowK[t]);
    } else if (t < 256) {
        int j = t - 128;
        atomicAdd(&colsum[colBase + j], lColS[j]);
        atomicMax(&colkey[colBase + j], lColK[j]);
    }
}

// ---------------- K2: per-row/col LSE + matches + cycle (merged) ------------
__global__ __launch_bounds__(256) void finalize_small_kernel(
    const float* __restrict__ rowsum, const ull* __restrict__ rowkey,
    const float* __restrict__ colsum, const ull* __restrict__ colkey,
    float* __restrict__ rowlse, float* __restrict__ collse,
    float* __restrict__ out_matches, float* __restrict__ out_cyc)
{
    int i = blockIdx.x * 256 + threadIdx.x;      // N == M
    if (i >= NROWS) return;
    rowlse[i] = logf(rowsum[i]);
    collse[i] = logf(colsum[i]);
    int mi = decodeKeyIdx(rowkey[i]);
    out_matches[i]         = (float)i;
    out_matches[NROWS + i] = (float)mi;
    out_cyc[i] = (decodeKeyIdx(colkey[mi]) == i) ? 1.0f : 0.0f;
}

// ---------------- K3: GEMM again -> write dense_logp + dense_p --------------
__global__ __launch_bounds__(512, 4) void gemm_write_kernel(
    const unsigned short* __restrict__ s1, const unsigned short* __restrict__ s2,
    const float* __restrict__ invT,
    const float* __restrict__ sq1, const float* __restrict__ sq2,
    const float* __restrict__ rowlse, const float* __restrict__ collse,
    float* __restrict__ logp_out, float* __restrict__ p_out)
{
    __shared__ unsigned short As[128 * 128];   // 32 KB
    __shared__ unsigned short Bs[128 * 128];   // 32 KB

    const int t = threadIdx.x;
    const int lane = t & 63;
    const int wave = t >> 6;
    const int wr = wave >> 2, wc = wave & 3;
    int rowBase, colBase;
    tileCoord(rowBase, colBase);

    floatx4 acc[4][2] = {};
    mfma_core(s1, s2, As, Bs, rowBase, colBase, lane, wave, wr, wc, acc);

    const int l15 = lane & 15;
    const int q   = lane >> 4;
    const float iT = *invT;
    float s1r[4], rl[4];
    #pragma unroll
    for (int mi = 0; mi < 4; ++mi) {
        int gi = rowBase + wr * 64 + mi * 16 + l15;
        s1r[mi] = sq1[gi] + EPSQ;
        rl[mi]  = rowlse[gi];
    }
    const int colLoc0 = wc * 32 + q * 4;
    float4 s2v[2], clv[2];
    #pragma unroll
    for (int ni = 0; ni < 2; ++ni) {
        s2v[ni] = *(const float4*)(sq2    + colBase + colLoc0 + ni * 16);
        clv[ni] = *(const float4*)(collse + colBase + colLoc0 + ni * 16);
    }

    #pragma unroll
    for (int mi = 0; mi < 4; ++mi) {
        const int gi = rowBase + wr * 64 + mi * 16 + l15;
        #pragma unroll
        for (int ni = 0; ni < 2; ++ni) {
            floatx4 ov, pv;
            #pragma unroll
            for (int r = 0; r < 4; ++r) {
                float sv2 = (r == 0) ? s2v[ni].x : (r == 1) ? s2v[ni].y
                          : (r == 2) ? s2v[ni].z : s2v[ni].w;
                float cl  = (r == 0) ? clv[ni].x : (r == 1) ? clv[ni].y
                          : (r == 2) ? clv[ni].z : clv[ni].w;
                float dd = s1r[mi] + sv2 - 2.0f * acc[mi][ni][r];
                float v = -iT * __builtin_amdgcn_sqrtf(fmaxf(dd, EPSQ));
                float o = (v - rl[mi]) + (v - cl);
                ov[r] = o;
                pv[r] = __expf(o);
            }
            size_t off = (size_t)gi * MCOLS + colBase + colLoc0 + ni * 16;
            __builtin_nontemporal_store(ov, (floatx4*)(logp_out + off));
            __builtin_nontemporal_store(pv, (floatx4*)(p_out + off));
        }
    }
}

extern "C" void kernel_launch(void* const* d_in, const int* in_sizes, int n_in,
                              void* d_out, int out_size, void* d_ws, size_t ws_size,
                              hipStream_t stream) {
    const float* d1   = (const float*)d_in[0];
    const float* d2   = (const float*)d_in[1];
    const float* invT = (const float*)d_in[2];

    float* out     = (float*)d_out;
    float* logp    = out;
    float* pout    = out + (size_t)NROWS * MCOLS;
    float* matches = out + 2ull * NROWS * MCOLS;
    float* cyc     = matches + 2 * NROWS;

    char* ws = (char*)d_ws;
    float* rowsum = (float*)(ws + 0);
    float* colsum = (float*)(ws + 24576);
    ull*   rowkey = (ull*)(ws + 49152);
    ull*   colkey = (ull*)(ws + 98304);
    float* sq1    = (float*)(ws + 147456);
    float* sq2    = (float*)(ws + 172032);
    float* rowlse = (float*)(ws + 196608);
    float* collse = (float*)(ws + 221184);
    unsigned short* s1 = (unsigned short*)(ws + 270336);            // [N][256] bf16
    unsigned short* s2 = (unsigned short*)(ws + 270336 + 3145728);  // [M][256] bf16

    (void)hipMemsetAsync(d_ws, 0, 147456, stream);     // rowsum/colsum/rowkey/colkey

    convert_kernel<<<(NROWS + MCOLS) / 4, 256, 0, stream>>>(d1, d2, s1, s2, sq1, sq2);

    gemm_reduce_kernel<<<NTC * NTC, 512, 0, stream>>>(
        s1, s2, invT, sq1, sq2, rowsum, colsum, rowkey, colkey);

    finalize_small_kernel<<<NROWS / 256, 256, 0, stream>>>(
        rowsum, rowkey, colsum, colkey, rowlse, collse, matches, cyc);

    gemm_write_kernel<<<NTC * NTC, 512, 0, stream>>>(
        s1, s2, invT, sq1, sq2, rowlse, collse, logp, pout);
}